// Round 7
// baseline (70.238 us; speedup 1.0000x reference)
//
#include <hip/hip_runtime.h>
#include <hip/hip_bf16.h>

#define N_PAIR  4096
#define N_ROW   8192
#define DIM     128
#define NBLOCKS 512   // k_simsum grid (8 x 64)

typedef __attribute__((ext_vector_type(4))) float   f32x4;
typedef __bf16 bf16x8 __attribute__((ext_vector_type(8)));

__device__ inline unsigned short f2bf(float x) {
    union { float f; unsigned int u; } c; c.f = x;
    unsigned int u = c.u;
    return (unsigned short)((u + 0x7fffu + ((u >> 16) & 1u)) >> 16);
}
__device__ inline float fast_exp2(float x) {
#if __has_builtin(__builtin_amdgcn_exp2f)
    return __builtin_amdgcn_exp2f(x);
#else
    float r; asm("v_exp_f32 %0, %1" : "=v"(r) : "v"(x)); return r;
#endif
}
__device__ inline float fast_log2(float x) {
#if __has_builtin(__builtin_amdgcn_logf)
    return __builtin_amdgcn_logf(x);
#else
    float r; asm("v_log_f32 %0, %1" : "=v"(r) : "v"(x)); return r;
#endif
}

// K1: interleave + L2-normalize -> zh bf16[8192][128]; partner dot -> pd;
//     zero rowsum + done-counter. One pair per wave.
__global__ __launch_bounds__(256) void k_prep(const float* __restrict__ zi,
                                              const float* __restrict__ zj,
                                              unsigned short* __restrict__ zh,
                                              float* __restrict__ pd,
                                              float* __restrict__ rowsum,
                                              unsigned int* __restrict__ cnt) {
    const int wid  = threadIdx.x >> 6;
    const int lane = threadIdx.x & 63;
    const int k    = blockIdx.x * 4 + wid;
    float2 a = *(const float2*)&zi[k * DIM + lane * 2];
    float2 b = *(const float2*)&zj[k * DIM + lane * 2];
    float ssi = a.x * a.x + a.y * a.y;
    float ssj = b.x * b.x + b.y * b.y;
    float dot = a.x * b.x + a.y * b.y;
#pragma unroll
    for (int off = 1; off < 64; off <<= 1) {
        ssi += __shfl_xor(ssi, off);
        ssj += __shfl_xor(ssj, off);
        dot += __shfl_xor(dot, off);
    }
    const float invi = rsqrtf(ssi), invj = rsqrtf(ssj);
    unsigned int wi = ((unsigned int)f2bf(a.y * invi) << 16) | f2bf(a.x * invi);
    unsigned int wj = ((unsigned int)f2bf(b.y * invj) << 16) | f2bf(b.x * invj);
    ((unsigned int*)zh)[(2 * k)     * (DIM / 2) + lane] = wi;
    ((unsigned int*)zh)[(2 * k + 1) * (DIM / 2) + lane] = wj;
    if (lane == 0) {
        pd[k] = dot * invi * invj;
        rowsum[2 * k]     = 0.f;
        rowsum[2 * k + 1] = 0.f;
        if (k == 0) cnt[0] = 0u;
    }
}

// K2: upper-triangle (wrapped-diagonal) S = Zh*Zh^T with transposed mfma(b,a).
//     Row-sums lane-local in registers; off-diag tiles add mirror col-sums via
//     l15-butterfly + atomics. Last block computes the loss inline.
__global__ __launch_bounds__(256, 2) void k_simsum(const unsigned short* __restrict__ zh,
                                                   float* __restrict__ rowsum,
                                                   const float* __restrict__ pd,
                                                   unsigned int* __restrict__ cnt,
                                                   float* __restrict__ out) {
    __shared__ unsigned short Bs[2][16384];         // 2 x 32 KB
    __shared__ int   s_last;
    __shared__ float wsum[4];
    const int tid  = threadIdx.x;
    const int lane = tid & 63;
    const int wid  = tid >> 6;
    const int wr   = wid >> 1, wc = wid & 1;
    const int l15  = lane & 15, lhi = lane >> 4;
    const int by   = blockIdx.y, cx = blockIdx.x;
    const int row0 = by * 128 + wr * 64;
    const int jbase = cx * 4;
    const int NT = 4 + (((by < 32) && (cx == (by & 7))) ? 1 : 0);

    // A fragments (t-invariant)
    bf16x8 a[4][4];
#pragma unroll
    for (int kk = 0; kk < 4; ++kk)
#pragma unroll
        for (int m = 0; m < 4; ++m)
            a[kk][m] = *(const bf16x8*)&zh[(row0 + m * 16 + l15) * DIM + kk * 32 + lhi * 8];

    const int r4  = lane >> 4;
    const int b16 = lane & 15;
    auto tile_bx = [&](int t) { int j = (t < 4) ? (jbase + t) : 32; return (by + j) & 63; };
    auto stage = [&](int ct, int buf) {
#pragma unroll
        for (int i = 0; i < 8; ++i) {
            const int chunk = wid * 8 + i;
            const int r = chunk * 4 + r4;
            const int g = b16 ^ (r & 7);
            const unsigned short* src = zh + (ct * 128 + r) * DIM + g * 8;
            __builtin_amdgcn_global_load_lds(
                (const __attribute__((address_space(1))) void*)src,
                (__attribute__((address_space(3))) void*)(&Bs[buf][chunk * 512]),
                16, 0, 0);
        }
    };

    const float K2E = 2.8853900817779268f;          // 2/ln2
    float rs[4] = {0.f, 0.f, 0.f, 0.f};

    stage(tile_bx(0), 0);
    asm volatile("s_waitcnt vmcnt(0)" ::: "memory");
    __builtin_amdgcn_s_barrier();

    int cur = 0;
#pragma unroll 1
    for (int t = 0; t < NT; ++t) {
        if (t + 1 < NT) stage(tile_bx(t + 1), cur ^ 1);
        const int bx = tile_bx(t);
        f32x4 accT[4][4] = {};
#pragma unroll
        for (int kk = 0; kk < 4; ++kk) {
            bf16x8 b[4];
#pragma unroll
            for (int n = 0; n < 4; ++n) {
                const int row = wc * 64 + n * 16 + l15;
                const int c   = (kk * 4 + lhi) ^ (l15 & 7);
                b[n] = *(const bf16x8*)&Bs[cur][row * 128 + c * 8];
            }
#pragma unroll
            for (int n = 0; n < 4; ++n)
#pragma unroll
                for (int m = 0; m < 4; ++m)
                    accT[n][m] = __builtin_amdgcn_mfma_f32_16x16x32_bf16(b[n], a[kk][m], accT[n][m], 0, 0, 0);
        }
        if (bx == by) {                              // diagonal: rows only, mask r==c
#pragma unroll
            for (int m = 0; m < 4; ++m) {
                const int rloc = wr * 64 + m * 16 + l15;
                float s0 = 0.f, s1 = 0.f;
#pragma unroll
                for (int n = 0; n < 4; ++n)
#pragma unroll
                    for (int r = 0; r < 4; ++r) {
                        const int cloc = wc * 64 + n * 16 + lhi * 4 + r;
                        float v = fast_exp2(K2E * accT[n][m][r]);
                        v = (cloc == rloc) ? 0.f : v;
                        if (n < 2) s0 += v; else s1 += v;
                    }
                rs[m] += s0 + s1;
            }
        } else {                                     // off-diag: rows + mirror cols
            float csum[4][4];
#pragma unroll
            for (int n = 0; n < 4; ++n)
#pragma unroll
                for (int r = 0; r < 4; ++r) csum[n][r] = 0.f;
#pragma unroll
            for (int m = 0; m < 4; ++m) {
                float s0 = 0.f, s1 = 0.f;
#pragma unroll
                for (int n = 0; n < 4; ++n)
#pragma unroll
                    for (int r = 0; r < 4; ++r) {
                        float v = fast_exp2(K2E * accT[n][m][r]);
                        if (n < 2) s0 += v; else s1 += v;
                        csum[n][r] += v;
                    }
                rs[m] += s0 + s1;
            }
            const int colw = bx * 128 + wc * 64;
#pragma unroll
            for (int n = 0; n < 4; ++n)
#pragma unroll
                for (int r = 0; r < 4; ++r) {
                    float c = csum[n][r];
                    c += __shfl_xor(c, 1);
                    c += __shfl_xor(c, 2);
                    c += __shfl_xor(c, 4);
                    c += __shfl_xor(c, 8);
                    if (l15 == 0) atomicAdd(&rowsum[colw + n * 16 + lhi * 4 + r], c);
                }
        }
        asm volatile("s_waitcnt vmcnt(0)" ::: "memory");
        __builtin_amdgcn_s_barrier();
        cur ^= 1;
    }

#pragma unroll
    for (int m = 0; m < 4; ++m) {
        rs[m] += __shfl_xor(rs[m], 16);
        rs[m] += __shfl_xor(rs[m], 32);
    }
    if (lane < 16) {
#pragma unroll
        for (int m = 0; m < 4; ++m)
            atomicAdd(&rowsum[row0 + m * 16 + lane], rs[m]);
    }

    // -------- last block computes the loss --------
    __threadfence();
    __syncthreads();
    if (tid == 0) s_last = (atomicAdd(cnt, 1u) == NBLOCKS - 1) ? 1 : 0;
    __syncthreads();
    if (s_last) {
        const float LN2 = 0.6931471805599453f;
        float local = 0.f;
        for (int i = tid; i < N_ROW; i += 256) {
            float rv = __hip_atomic_load(&rowsum[i], __ATOMIC_RELAXED, __HIP_MEMORY_SCOPE_AGENT);
            local += fast_log2(rv) * LN2 - 2.f * pd[i >> 1];
        }
#pragma unroll
        for (int off = 1; off < 64; off <<= 1) local += __shfl_xor(local, off);
        if (lane == 0) wsum[wid] = local;
        __syncthreads();
        if (tid == 0)
            out[0] = (wsum[0] + wsum[1] + wsum[2] + wsum[3]) * (1.f / (float)N_ROW);
    }
}

extern "C" void kernel_launch(void* const* d_in, const int* in_sizes, int n_in,
                              void* d_out, int out_size, void* d_ws, size_t ws_size,
                              hipStream_t stream) {
    const float* zi = (const float*)d_in[0];
    const float* zj = (const float*)d_in[1];
    char* ws = (char*)d_ws;
    unsigned short* zh = (unsigned short*)ws;                          // 2 MiB
    float* rowsum      = (float*)(ws + 2 * 1024 * 1024);               // 32 KiB
    float* pd          = (float*)(ws + 2 * 1024 * 1024 + 32 * 1024);   // 16 KiB
    unsigned int* cnt  = (unsigned int*)(ws + 2 * 1024 * 1024 + 48 * 1024);

    k_prep<<<N_PAIR / 4, 256, 0, stream>>>(zi, zj, zh, pd, rowsum, cnt);
    dim3 grid(8, 64);
    k_simsum<<<grid, 256, 0, stream>>>(zh, rowsum, pd, cnt, (float*)d_out);
}

// Round 8
// 35.817 us; speedup vs baseline: 1.9610x; 1.9610x over previous
//
#include <hip/hip_runtime.h>
#include <hip/hip_bf16.h>

#define N_PAIR 4096
#define N_ROW  8192
#define DIM    128
#define NX     8     // col-tiles swept per block

typedef __attribute__((ext_vector_type(4))) float   f32x4;
typedef __bf16 bf16x8 __attribute__((ext_vector_type(8)));

__device__ inline unsigned short f2bf(float x) {
    union { float f; unsigned int u; } c; c.f = x;
    unsigned int u = c.u;
    return (unsigned short)((u + 0x7fffu + ((u >> 16) & 1u)) >> 16);
}
__device__ inline float fast_exp2(float x) {
#if __has_builtin(__builtin_amdgcn_exp2f)
    return __builtin_amdgcn_exp2f(x);
#else
    float r; asm("v_exp_f32 %0, %1" : "=v"(r) : "v"(x)); return r;
#endif
}
__device__ inline float fast_log2(float x) {
#if __has_builtin(__builtin_amdgcn_logf)
    return __builtin_amdgcn_logf(x);
#else
    float r; asm("v_log_f32 %0, %1" : "=v"(r) : "v"(x)); return r;
#endif
}

// K1: interleave + L2-normalize -> zh bf16[8192][128]; partner dot -> pd;
//     zero rowsum. One pair per wave.
__global__ __launch_bounds__(256) void k_prep(const float* __restrict__ zi,
                                              const float* __restrict__ zj,
                                              unsigned short* __restrict__ zh,
                                              float* __restrict__ pd,
                                              float* __restrict__ rowsum) {
    const int wid  = threadIdx.x >> 6;
    const int lane = threadIdx.x & 63;
    const int k    = blockIdx.x * 4 + wid;
    float2 a = *(const float2*)&zi[k * DIM + lane * 2];
    float2 b = *(const float2*)&zj[k * DIM + lane * 2];
    float ssi = a.x * a.x + a.y * a.y;
    float ssj = b.x * b.x + b.y * b.y;
    float dot = a.x * b.x + a.y * b.y;
#pragma unroll
    for (int off = 1; off < 64; off <<= 1) {
        ssi += __shfl_xor(ssi, off);
        ssj += __shfl_xor(ssj, off);
        dot += __shfl_xor(dot, off);
    }
    const float invi = rsqrtf(ssi), invj = rsqrtf(ssj);
    unsigned int wi = ((unsigned int)f2bf(a.y * invi) << 16) | f2bf(a.x * invi);
    unsigned int wj = ((unsigned int)f2bf(b.y * invj) << 16) | f2bf(b.x * invj);
    ((unsigned int*)zh)[(2 * k)     * (DIM / 2) + lane] = wi;
    ((unsigned int*)zh)[(2 * k + 1) * (DIM / 2) + lane] = wj;
    if (lane == 0) {
        pd[k] = dot * invi * invj;
        rowsum[2 * k]     = 0.f;
        rowsum[2 * k + 1] = 0.f;
    }
}

// K2: full-matrix S = Zh*Zh^T, R6 dataflow but 8 waves/block (512 thr):
//     wave = 32 rows x 64 cols -> 4 waves/SIMD for latency hiding.
//     B double-buffered in LDS via global_load_lds w16 (linear dest +
//     inverse-swizzled source, XOR-swizzled ds_read). Transposed mfma(b,a)
//     -> output row lane-local -> rowsum is register FMA.
__global__ __launch_bounds__(512, 4) void k_simsum(const unsigned short* __restrict__ zh,
                                                   float* __restrict__ rowsum) {
    __shared__ unsigned short Bs[2][16384];         // 2 x 32 KB (128 rows x 256B)
    const int tid  = threadIdx.x;
    const int lane = tid & 63;
    const int wid  = tid >> 6;                      // 0..7
    const int wr   = wid >> 1, wc = wid & 1;        // wr: 32-row strip, wc: 64-col strip
    const int l15  = lane & 15, lhi = lane >> 4;
    const int by   = blockIdx.y;
    const int bx0  = blockIdx.x * NX;
    const int row0 = by * 128 + wr * 32;            // wave's A-row base

    // A fragments, invariant across the col-tile sweep: a[kk][m], m in {0,1}
    bf16x8 a[4][2];
#pragma unroll
    for (int kk = 0; kk < 4; ++kk)
#pragma unroll
        for (int m = 0; m < 2; ++m)
            a[kk][m] = *(const bf16x8*)&zh[(row0 + m * 16 + l15) * DIM + kk * 32 + lhi * 8];

    // stage col-tile ct into Bs[buf]: LDS linear, global source pre-swizzled
    // (chunk16 g = b16 ^ (row&7)); ds_read applies the same XOR (involution).
    const int r4  = lane >> 4;
    const int b16 = lane & 15;
    auto stage = [&](int ct, int buf) {
#pragma unroll
        for (int i = 0; i < 4; ++i) {
            const int chunk = wid * 4 + i;          // 0..31 (1 KB each)
            const int r = chunk * 4 + r4;           // 0..127
            const int g = b16 ^ (r & 7);
            const unsigned short* src = zh + (ct * 128 + r) * DIM + g * 8;
            __builtin_amdgcn_global_load_lds(
                (const __attribute__((address_space(1))) void*)src,
                (__attribute__((address_space(3))) void*)(&Bs[buf][chunk * 512]),
                16, 0, 0);
        }
    };

    const float K2E = 2.8853900817779268f;          // 2/ln2: exp(2s)=exp2(K2E*s)
    float rs[2] = {0.f, 0.f};

    stage(bx0, 0);
    asm volatile("s_waitcnt vmcnt(0)" ::: "memory");
    __builtin_amdgcn_s_barrier();

    int cur = 0;
#pragma unroll 1
    for (int t = 0; t < NX; ++t) {
        if (t + 1 < NX) stage(bx0 + t + 1, cur ^ 1);   // prefetch next tile
        const int bx = bx0 + t;
        f32x4 accT[4][2] = {};                      // [n][m]: reg->col, l15->row
#pragma unroll
        for (int kk = 0; kk < 4; ++kk) {
            bf16x8 b[4];
#pragma unroll
            for (int n = 0; n < 4; ++n) {
                const int row = wc * 64 + n * 16 + l15;
                const int c   = (kk * 4 + lhi) ^ (l15 & 7);
                b[n] = *(const bf16x8*)&Bs[cur][row * 128 + c * 8];
            }
#pragma unroll
            for (int n = 0; n < 4; ++n)
#pragma unroll
                for (int m = 0; m < 2; ++m)
                    accT[n][m] = __builtin_amdgcn_mfma_f32_16x16x32_bf16(b[n], a[kk][m], accT[n][m], 0, 0, 0);
        }
        if (bx == by) {                              // diagonal tile: mask col==row
#pragma unroll
            for (int m = 0; m < 2; ++m) {
                const int rloc = wr * 32 + m * 16 + l15;
                float s0 = 0.f, s1 = 0.f;
#pragma unroll
                for (int n = 0; n < 4; ++n)
#pragma unroll
                    for (int r = 0; r < 4; ++r) {
                        const int cloc = wc * 64 + n * 16 + lhi * 4 + r;
                        float v = fast_exp2(K2E * accT[n][m][r]);
                        v = (cloc == rloc) ? 0.f : v;
                        if (n < 2) s0 += v; else s1 += v;
                    }
                rs[m] += s0 + s1;
            }
        } else {
#pragma unroll
            for (int m = 0; m < 2; ++m) {
                float s0 = 0.f, s1 = 0.f;
#pragma unroll
                for (int n = 0; n < 4; ++n)
#pragma unroll
                    for (int r = 0; r < 4; ++r) {
                        float v = fast_exp2(K2E * accT[n][m][r]);
                        if (n < 2) s0 += v; else s1 += v;
                    }
                rs[m] += s0 + s1;
            }
        }
        asm volatile("s_waitcnt vmcnt(0)" ::: "memory");   // next tile staged
        __builtin_amdgcn_s_barrier();                      // + all reads of cur done
        cur ^= 1;
    }

    // rows are per-l15; fold the 4 lhi groups, then 2 atomics x 16 lanes per wave
#pragma unroll
    for (int m = 0; m < 2; ++m) {
        rs[m] += __shfl_xor(rs[m], 16);
        rs[m] += __shfl_xor(rs[m], 32);
    }
    if (lane < 16) {
#pragma unroll
        for (int m = 0; m < 2; ++m)
            atomicAdd(&rowsum[row0 + m * 16 + lane], rs[m]);
    }
}

// K3: single block, 1024 threads: direct write of the mean (no memset, no atomics).
__global__ __launch_bounds__(1024) void k_loss(const float* __restrict__ rowsum,
                                               const float* __restrict__ pd,
                                               float* __restrict__ out) {
    const int tid  = threadIdx.x;
    const int lane = tid & 63;
    const int wid  = tid >> 6;
    const float LN2 = 0.6931471805599453f;
    float local = 0.f;
    for (int i = tid; i < N_ROW; i += 1024)
        local += fast_log2(rowsum[i]) * LN2 - 2.f * pd[i >> 1];
#pragma unroll
    for (int off = 1; off < 64; off <<= 1) local += __shfl_xor(local, off);
    __shared__ float wsum[16];
    if (lane == 0) wsum[wid] = local;
    __syncthreads();
    if (tid == 0) {
        float s = 0.f;
#pragma unroll
        for (int w = 0; w < 16; ++w) s += wsum[w];
        out[0] = s * (1.f / (float)N_ROW);
    }
}

extern "C" void kernel_launch(void* const* d_in, const int* in_sizes, int n_in,
                              void* d_out, int out_size, void* d_ws, size_t ws_size,
                              hipStream_t stream) {
    const float* zi = (const float*)d_in[0];
    const float* zj = (const float*)d_in[1];
    char* ws = (char*)d_ws;
    unsigned short* zh = (unsigned short*)ws;                     // 2 MiB
    float* rowsum = (float*)(ws + 2 * 1024 * 1024);               // 32 KiB
    float* pd     = (float*)(ws + 2 * 1024 * 1024 + 32 * 1024);   // 16 KiB

    k_prep<<<N_PAIR / 4, 256, 0, stream>>>(zi, zj, zh, pd, rowsum);
    dim3 grid(64 / NX, 64);
    k_simsum<<<grid, 512, 0, stream>>>(zh, rowsum);
    k_loss<<<1, 1024, 0, stream>>>(rowsum, pd, (float*)d_out);
}